// Round 17
// baseline (5256.625 us; speedup 1.0000x reference)
//
#include <hip/hip_runtime.h>

// ---------------------------------------------------------------------------
// 2-layer "bidirectional" LSTM generator, B=2048, T=128, HID=150.
// R17 = R16 (128 WGs x 16 rows, fastest: 4.92 ms) + deeper/cheaper pipeline:
//  - ring 5 -> 8 slots/wave (8KB); t-loop unrolled x2 so slot = FG%8 is
//    compile-time consistent (200-frag supercycle, 200%8=0)
//  - refill distance 6 (< ring 8): DMA at consume-F writes the slot read at
//    F-2 -> guard is lgkmcnt(2), NOT a full lgkmcnt(0) drain (R13/R16 paid
//    ~120cyc serialized drain per frag)
//  - waitv(5): 6 DMAs outstanding, wait only for the oldest
// Rest identical to R16: per-wave linear f16 A-frag streams, biases folded
// (y cols 152-156, 1.0 col 157, b_* as weight cols), lgkm-only phase
// barriers, acc[5]=20 AGPR, c-state in regs, 1 N-tile/wave.
// LDS: tile 16x1312=20992 | pjl @20992 (10240) | rings @31232 + w*8192.
// Total 162304 B (fits 160 KiB).
// ---------------------------------------------------------------------------

typedef _Float16 f16;
typedef _Float16 f16x8 __attribute__((ext_vector_type(8)));
typedef _Float16 f16x2v __attribute__((ext_vector_type(2)));
typedef float    f32x4 __attribute__((ext_vector_type(4)));

#define LOG2E 1.44269504f

__device__ __forceinline__ float sigm_(float x) {
    float e = __builtin_amdgcn_exp2f(-LOG2E * x);
    return __builtin_amdgcn_rcpf(1.f + e);
}
__device__ __forceinline__ float tanh_(float x) {
    float e = __builtin_amdgcn_exp2f(2.f * LOG2E * x);
    return 1.f - 2.f * __builtin_amdgcn_rcpf(1.f + e);
}

// vmcnt(5): wait until <=5 VMEM outstanding (oldest of 6 ring DMAs landed)
__device__ __forceinline__ void waitv5() {
    __builtin_amdgcn_s_waitcnt(0x0F75);
    __builtin_amdgcn_sched_barrier(0);
}
// lgkmcnt(2): the ds_read from 2 frags ago is complete (slot-reuse guard)
__device__ __forceinline__ void waitlgkm2() {
    __builtin_amdgcn_s_waitcnt(0xC27F);
    __builtin_amdgcn_sched_barrier(0);
}
__device__ __forceinline__ void bar_lgkm() {
    asm volatile("s_waitcnt lgkmcnt(0)" ::: "memory");
    __builtin_amdgcn_s_barrier();
    asm volatile("" ::: "memory");
}

typedef const __attribute__((address_space(1))) void* gas_t;
typedef __attribute__((address_space(3))) void* las_t;

__device__ __forceinline__ void dma_frag(const f16* wsrc, char* ringb, int F, int slot) {
    __builtin_amdgcn_global_load_lds((gas_t)(wsrc + (size_t)F * 512),
                                     (las_t)(ringb + slot * 1024), 16, 0, 0);
}

// ---------------- ws layout (bytes) ----------------
#define OFF_CINIT 2621440
#define OFF_WSTR  7864320
#define OFF_PWPJ  9502720

__device__ float dot105(const float* __restrict__ noise,
                        const float* __restrict__ targ,
                        const float* __restrict__ msk,
                        const float* __restrict__ Wrow, int bb) {
    float s = 0.f;
    const float* nz = noise + (size_t)bb * 100;
#pragma unroll 4
    for (int k = 0; k < 100; ++k) s += nz[k] * Wrow[k];
    s += targ[bb*2+0]*Wrow[100] + targ[bb*2+1]*Wrow[101];
    s += msk[bb*3+0]*Wrow[102] + msk[bb*3+1]*Wrow[103] + msk[bb*3+2]*Wrow[104];
    return s;
}

// HINIT tile regions [h1b,_,1@157 | h0f,x,y,1 | h0b,x,y,1 | h1f] + CINIT.
// Replicates torch's (B,1200).view(8,B,150) on the row-major init buffer.
__global__ void k_init(const float* __restrict__ noise, const float* __restrict__ targ,
                       const float* __restrict__ msk,
                       const float* __restrict__ Wih, const float* __restrict__ bih,
                       const float* __restrict__ Wtk, const float* __restrict__ btk,
                       f16* __restrict__ hinit, float* __restrict__ cinitp) {
    int gid = blockIdx.x * 256 + threadIdx.x;   // 2048*1280 exact
    int b = gid / 1280, c = gid % 1280;
    if (c < 640) {
        int reg = c / 160, loc = c % 160;
        float v = 0.f;
        if (loc < 150) {
            int q = (reg == 0) ? 3 : (reg == 1) ? 0 : (reg == 2) ? 1 : 2; // h1b,h0f,h0b,h1f
            size_t i = (size_t)q * 2048 * 150 + (size_t)b * 150 + loc;
            int bb = (int)(i / 1200), rr = (int)(i % 1200);
            v = dot105(noise, targ, msk, Wih + (size_t)rr * 105, bb) + bih[rr];
        } else if (loc == 157) {
            if (reg != 3) v = 1.0f;             // bias column (b_l0/b_l1/b_proj)
        } else if (reg == 1 || reg == 2) {
            if (loc < 152) {                    // x0
                int o = loc - 150;
                v = dot105(noise, targ, msk, Wtk + o * 105, b) + btk[o];
            } else if (loc == 152) v = targ[b*2+0];   // y
            else if (loc == 153)   v = targ[b*2+1];
            else if (loc <= 156)   v = msk[b*3 + (loc - 154)];
        }
        hinit[(size_t)b * 640 + c] = (f16)v;
    } else {
        int idx = c - 640;                       // layer*320 + d*160 + j
        int layer = idx / 320, r = idx % 320, d = r / 160, j = r % 160;
        float v = 0.f;
        if (j < 150) {
            int q = 4 + layer * 2 + d;
            size_t i = (size_t)q * 2048 * 150 + (size_t)b * 150 + j;
            int bb = (int)(i / 1200), rr = (int)(i % 1200);
            v = dot105(noise, targ, msk, Wih + (size_t)rr * 105, bb) + bih[rr];
        }
        cinitp[(((size_t)layer * 2048 + b) * 2 + d) * 160 + j] = v;
    }
}

// Per-wave linear A-frag streams [16][100][512] + proj frags (10 nonzero ks).
__global__ void k_pack(const float* __restrict__ Wih0, const float* __restrict__ Whh0,
                       const float* __restrict__ bl0,
                       const float* __restrict__ Wih1, const float* __restrict__ Whh1,
                       const float* __restrict__ bl1,
                       const float* __restrict__ Wp,   const float* __restrict__ bpj,
                       f16* __restrict__ wstream, f16* __restrict__ pwpj) {
    int gid = blockIdx.x * 256 + threadIdx.x;   // 824,320 exact
    if (gid < 819200) {           // [w][100][64][8]
        int e = gid & 7, l = (gid >> 3) & 63;
        int f = (gid >> 9) % 100, w = gid / 51200;
        int r16 = l & 15, k8 = (l >> 4) * 8 + e;
        float v = 0.f;
        if (f < 25) {             // L0
            int ks = f / 5, m = f % 5;
            int mt = w * 5 + m, d = mt / 40, jt = mt % 40;
            int j = jt * 4 + (r16 >> 2), g = r16 & 3;
            int k = ks * 32 + k8;
            if (j < 150) {
                int R = d * 600 + g * 150 + j;
                if (k < 150)       v = Whh0[(size_t)R * 150 + k];
                else if (k < 157)  v = Wih0[(size_t)R * 7 + (k - 150)]; // x+y
                else if (k == 157) v = bl0[R];
            }
        } else {                  // L1
            int fc = f - 25, ks = fc / 5, m = fc % 5;
            int mt = w * 5 + m, d = mt / 40, jt = mt % 40;
            int j = jt * 4 + (r16 >> 2), g = r16 & 3;
            int k = ks * 32 + k8;
            if (j < 150) {
                int R = d * 600 + g * 150 + j;
                if (d == 0) {    // fwd: [h0f,x,y,1 | h0b,x,y,1 | h1f]
                    if (k < 150)                  v = Wih1[(size_t)R * 300 + k];
                    else if (k == 157)            v = bl1[R];
                    else if (k >= 160 && k < 310) v = Wih1[(size_t)R * 300 + (k - 10)];
                    else if (k >= 320 && k < 470) v = Whh1[(size_t)R * 150 + (k - 320)];
                } else {         // bwd: [h1b,_,1 | h0f,x,y,1 | h0b,x,y,1]
                    if (k < 150)                  v = Whh1[(size_t)R * 150 + k];
                    else if (k >= 160 && k < 310) v = Wih1[(size_t)R * 300 + (k - 160)];
                    else if (k == 317)            v = bl1[R];
                    else if (k >= 320 && k < 470) v = Wih1[(size_t)R * 300 + (k - 170)];
                }
            }
        }
        wstream[gid] = (f16)v;
    } else {                      // proj frags [10][64][8]: ks = ksi<5?ksi:ksi+10
        int pg = gid - 819200;
        int e = pg & 7, l = (pg >> 3) & 63, ksi = pg >> 9;
        int ks = ksi < 5 ? ksi : ksi + 10;
        int r16 = l & 15, k = ks * 32 + (l >> 4) * 8 + e;
        float v = 0.f;
        if (r16 < 2) {            // h1b 0..149 | bpj col 157 | h1f 480..629
            if (k < 150)                  v = Wp[r16 * 300 + 150 + k];
            else if (k == 157)            v = bpj[r16];
            else if (k >= 480 && k < 630) v = Wp[r16 * 300 + (k - 480)];
        }
        pwpj[pg] = (f16)v;
    }
}

// ---------------------------------------------------------------------------
// Main persistent kernel: 128 WGs x 1024 thr (16 waves), 16 batch rows/WG.
// Wave w owns M-tiles [5w,5w+5) (w<8 fwd, w>=8 bwd) x ONE N-tile.
// ---------------------------------------------------------------------------
__global__ __launch_bounds__(1024) void lstm_main(
    const f16* __restrict__ hinit, const float* __restrict__ cinit,
    const f16* __restrict__ wstream, const f16* __restrict__ pwpj,
    const int* __restrict__ lengths, float* __restrict__ out) {
    __shared__ f16 lds[81152];
    char* ldsb = (char*)lds;
    const int tid = threadIdx.x;
    const int w = tid >> 6, l = tid & 63;
    const int b0 = blockIdx.x * 16;
    const int l15 = l & 15, lg = l >> 4;
    const int dirw = w >> 3;

    // ---- stage LDS ----
    for (int it = tid; it < 16 * 80; it += 1024) {        // tile <- HINIT
        int row = it / 80, c8 = (it % 80) * 8;
        f16x8 v = *(const f16x8*)(hinit + (size_t)(b0 + row) * 640 + c8);
        int byte = row * 1312 + c8 * 2;  byte ^= (row & 7) << 4;
        *(f16x8*)(ldsb + byte) = v;
    }
    if (tid < 640)                                        // pjl (10 KB)
        *(f16x8*)(ldsb + 20992 + tid * 16) = *(const f16x8*)(pwpj + tid * 8);

    const int jb = ((w * 5) % 40) * 4 + lg;               // jj(m) = jb + 4m

    float c0s[5], c1s[5];
#pragma unroll
    for (int m = 0; m < 5; ++m) {
        int b = b0 + l15;
        c0s[m] = cinit[((size_t)b * 2 + dirw) * 160 + jb + 4 * m];
        c1s[m] = cinit[(((size_t)2048 + b) * 2 + dirw) * 160 + jb + 4 * m];
    }

    int lenb = 0;
    if (w == 0 && l < 16) lenb = lengths[b0 + l];

    const int baseL0 = 160 + dirw * 160;
    const int baseL1 = dirw ? 0 : 160;
    const int hw1    = dirw ? 0 : 480;
    const f16* wsrc = wstream + (size_t)w * 51200 + l * 8;
    char* ringb = ldsb + 31232 + w * 8192;

    // ring prologue: frags 0..5 into slots 0..5 (6 outstanding)
#pragma unroll
    for (int F = 0; F < 6; ++F) dma_frag(wsrc, ringb, F, F);

    __syncthreads();

// One LSTM step; TB in {0,1} selects the supercycle half so that
// slot = FG % 8 is compile-time and consistent (200 % 8 == 0).
#define STEP(TB)                                                              \
    {                                                                         \
        f32x4 acc[5];                                                         \
        _Pragma("unroll")                                                     \
        for (int m = 0; m < 5; ++m) acc[m] = (f32x4){0.f, 0.f, 0.f, 0.f};     \
        _Pragma("unroll")                                                     \
        for (int ks = 0; ks < 5; ++ks) {                                      \
            int byteb = l15 * 1312 + (baseL0 + ks * 32 + lg * 8) * 2;         \
            byteb ^= (l15 & 7) << 4;                                          \
            f16x8 bfr = *(const f16x8*)(ldsb + byteb);                        \
            _Pragma("unroll")                                                 \
            for (int m = 0; m < 5; ++m) {                                     \
                const int FG = (TB) * 100 + ks * 5 + m;                       \
                waitv5();                                                     \
                f16x8 a = *(const f16x8*)(ringb + (FG & 7) * 1024 + l * 16);  \
                waitlgkm2();                                                  \
                dma_frag(wsrc, ringb, (FG + 6) % 100, (FG + 6) & 7);          \
                acc[m] = __builtin_amdgcn_mfma_f32_16x16x32_f16(a, bfr, acc[m], 0, 0, 0); \
            }                                                                 \
        }                                                                     \
        bar_lgkm();                                                           \
        _Pragma("unroll")                                                     \
        for (int m = 0; m < 5; ++m) {                                         \
            float gi = sigm_(acc[m][0]);                                      \
            float gf = sigm_(acc[m][1]);                                      \
            float gg = tanh_(acc[m][2]);                                      \
            float go = sigm_(acc[m][3]);                                      \
            float c = gf * c0s[m] + gi * gg;                                  \
            c0s[m] = c;                                                       \
            float h = go * tanh_(c);                                          \
            if (jb + 4 * m < 150) {                                           \
                int byte = l15 * 1312 + (baseL0 + jb + 4 * m) * 2;            \
                byte ^= (l15 & 7) << 4;                                       \
                *(f16*)(ldsb + byte) = (f16)h;                                \
            }                                                                 \
        }                                                                     \
        bar_lgkm();                                                           \
        _Pragma("unroll")                                                     \
        for (int m = 0; m < 5; ++m) acc[m] = (f32x4){0.f, 0.f, 0.f, 0.f};     \
        _Pragma("unroll")                                                     \
        for (int ks = 0; ks < 15; ++ks) {                                     \
            int byteb = l15 * 1312 + (baseL1 + ks * 32 + lg * 8) * 2;         \
            byteb ^= (l15 & 7) << 4;                                          \
            f16x8 bfr = *(const f16x8*)(ldsb + byteb);                        \
            _Pragma("unroll")                                                 \
            for (int m = 0; m < 5; ++m) {                                     \
                const int FG = (TB) * 100 + 25 + ks * 5 + m;                  \
                waitv5();                                                     \
                f16x8 a = *(const f16x8*)(ringb + (FG & 7) * 1024 + l * 16);  \
                waitlgkm2();                                                  \
                dma_frag(wsrc, ringb, (FG + 6) % 100, (FG + 6) & 7);          \
                acc[m] = __builtin_amdgcn_mfma_f32_16x16x32_f16(a, bfr, acc[m], 0, 0, 0); \
            }                                                                 \
        }                                                                     \
        bar_lgkm();                                                           \
        _Pragma("unroll")                                                     \
        for (int m = 0; m < 5; ++m) {                                         \
            float gi = sigm_(acc[m][0]);                                      \
            float gf = sigm_(acc[m][1]);                                      \
            float gg = tanh_(acc[m][2]);                                      \
            float go = sigm_(acc[m][3]);                                      \
            float c = gf * c1s[m] + gi * gg;                                  \
            c1s[m] = c;                                                       \
            float h = go * tanh_(c);                                          \
            if (jb + 4 * m < 150) {                                           \
                int byte = l15 * 1312 + (hw1 + jb + 4 * m) * 2;               \
                byte ^= (l15 & 7) << 4;                                       \
                *(f16*)(ldsb + byte) = (f16)h;                                \
            }                                                                 \
        }                                                                     \
        bar_lgkm();                                                           \
        if (w == 0) {                                                         \
            f32x4 ap = (f32x4){0.f, 0.f, 0.f, 0.f};                           \
            _Pragma("unroll")                                                 \
            for (int ksi = 0; ksi < 10; ++ksi) {                              \
                int ks = ksi < 5 ? ksi : ksi + 10;                            \
                int byte = l15 * 1312 + (ks * 32 + lg * 8) * 2;               \
                byte ^= (l15 & 7) << 4;                                       \
                f16x8 bfp = *(const f16x8*)(ldsb + byte);                     \
                f16x8 a = *(const f16x8*)(ldsb + 20992 + ksi * 1024 + l * 16);\
                ap = __builtin_amdgcn_mfma_f32_16x16x32_f16(a, bfp, ap, 0, 0, 0); \
            }                                                                 \
            if (l < 16) {                                                     \
                float o0 = ap[0], o1 = ap[1];                                 \
                int b = b0 + l;                                               \
                bool live = (t < lenb);                                       \
                *(float2*)(out + ((size_t)b * 128 + t) * 2) =                 \
                    make_float2(live ? o0 : 0.f, live ? o1 : 0.f);            \
                f16x2v xv = {(f16)o0, (f16)o1};                               \
                int byte1 = l * 1312 + 620;  byte1 ^= (l & 7) << 4;           \
                *(f16x2v*)(ldsb + byte1) = xv;                                \
                int byte2 = l * 1312 + 940;  byte2 ^= (l & 7) << 4;           \
                *(f16x2v*)(ldsb + byte2) = xv;                                \
            }                                                                 \
        }                                                                     \
        bar_lgkm();                                                           \
        ++t;                                                                  \
    }

    int t = 0;
#pragma unroll 1
    for (int th = 0; th < 64; ++th) {
        STEP(0)
        STEP(1)
    }
#undef STEP
}

extern "C" void kernel_launch(void* const* d_in, const int* in_sizes, int n_in,
                              void* d_out, int out_size, void* d_ws, size_t ws_size,
                              hipStream_t stream) {
    const float* noise = (const float*)d_in[0];
    const float* targ  = (const float*)d_in[1];
    const float* msk   = (const float*)d_in[2];
    const int*   lens  = (const int*)d_in[3];
    const float* Wih0  = (const float*)d_in[5];
    const float* Whh0  = (const float*)d_in[6];
    const float* bl0   = (const float*)d_in[7];
    const float* Wih1  = (const float*)d_in[8];
    const float* Whh1  = (const float*)d_in[9];
    const float* bl1   = (const float*)d_in[10];
    const float* Wp    = (const float*)d_in[11];
    const float* bpj   = (const float*)d_in[12];
    const float* Wit   = (const float*)d_in[13];
    const float* bit   = (const float*)d_in[14];
    const float* Wtk   = (const float*)d_in[15];
    const float* btk   = (const float*)d_in[16];

    char* ws = (char*)d_ws;
    f16*   HINIT = (f16*)(ws);
    float* CINIT = (float*)(ws + OFF_CINIT);
    f16*   WSTR  = (f16*)(ws + OFF_WSTR);
    f16*   PWPJ  = (f16*)(ws + OFF_PWPJ);

    hipLaunchKernelGGL(k_init,  dim3(10240), dim3(256), 0, stream,
                       noise, targ, msk, Wit, bit, Wtk, btk, HINIT, CINIT);
    hipLaunchKernelGGL(k_pack,  dim3(3220), dim3(256), 0, stream,
                       Wih0, Whh0, bl0, Wih1, Whh1, bl1, Wp, bpj, WSTR, PWPJ);
    hipLaunchKernelGGL(lstm_main, dim3(128), dim3(1024), 0, stream,
                       HINIT, CINIT, WSTR, PWPJ, lens, (float*)d_out);
}

// Round 18
// 2074.347 us; speedup vs baseline: 2.5341x; 2.5341x over previous
//
#include <hip/hip_runtime.h>

// ---------------------------------------------------------------------------
// 2-layer "bidirectional" LSTM generator, B=2048, T=128, HID=150.
// R18 = R16 (best: 4.92 ms) with the two GEMM ks loops made RUNTIME loops
// (#pragma unroll 1). The ~96 MB/call WRITE_SIZE (vs 2 MB of out stores)
// that survived every round is scratch spill from the giant fully-unrolled
// step body; its L2 traffic (~1.5 MB/XCD/step + read-back) is what evicts
// the 1.6 MB weight set (23% miss -> FETCH 6 GB == dur at 1250 GB/s).
// With a 5-slot ring and 5 frags/ks, slot = F%5 = m is compile-time even
// with runtime ks -> tiny loop body (~25 instrs) that cannot spill.
// Everything else byte-identical to R16: 128 WGs x 1024 thr, 16 rows/WG,
// per-frag waitv(4)+lgkm0 discipline, refill (F+5), lgkm-only barriers,
// biases folded into weights, acc[5] AGPR, c-state in regs.
// LDS: tile 16x1312=20992 | pjl @20992 (10240) | rings @31232 + w*5120.
// ---------------------------------------------------------------------------

typedef _Float16 f16;
typedef _Float16 f16x8 __attribute__((ext_vector_type(8)));
typedef _Float16 f16x2v __attribute__((ext_vector_type(2)));
typedef float    f32x4 __attribute__((ext_vector_type(4)));

#define LOG2E 1.44269504f

__device__ __forceinline__ float sigm_(float x) {
    float e = __builtin_amdgcn_exp2f(-LOG2E * x);
    return __builtin_amdgcn_rcpf(1.f + e);
}
__device__ __forceinline__ float tanh_(float x) {
    float e = __builtin_amdgcn_exp2f(2.f * LOG2E * x);
    return 1.f - 2.f * __builtin_amdgcn_rcpf(1.f + e);
}

// wait until at most 4 VMEM ops outstanding (oldest ring DMA landed)
__device__ __forceinline__ void waitv4() {
    __builtin_amdgcn_s_waitcnt(0x0F74);
    __builtin_amdgcn_sched_barrier(0);
}
// drain LDS ops (slot-reuse guard); leave VMEM in flight
__device__ __forceinline__ void waitlgkm0() {
    asm volatile("s_waitcnt lgkmcnt(0)" ::: "memory");
    __builtin_amdgcn_sched_barrier(0);
}
__device__ __forceinline__ void bar_lgkm() {
    asm volatile("s_waitcnt lgkmcnt(0)" ::: "memory");
    __builtin_amdgcn_s_barrier();
    asm volatile("" ::: "memory");
}

typedef const __attribute__((address_space(1))) void* gas_t;
typedef __attribute__((address_space(3))) void* las_t;

__device__ __forceinline__ void dma_frag(const f16* wsrc, char* ringb, int F, int slot) {
    __builtin_amdgcn_global_load_lds((gas_t)(wsrc + (size_t)F * 512),
                                     (las_t)(ringb + slot * 1024), 16, 0, 0);
}

// ---------------- ws layout (bytes) ----------------
#define OFF_CINIT 2621440
#define OFF_WSTR  7864320
#define OFF_PWPJ  9502720

__device__ float dot105(const float* __restrict__ noise,
                        const float* __restrict__ targ,
                        const float* __restrict__ msk,
                        const float* __restrict__ Wrow, int bb) {
    float s = 0.f;
    const float* nz = noise + (size_t)bb * 100;
#pragma unroll 4
    for (int k = 0; k < 100; ++k) s += nz[k] * Wrow[k];
    s += targ[bb*2+0]*Wrow[100] + targ[bb*2+1]*Wrow[101];
    s += msk[bb*3+0]*Wrow[102] + msk[bb*3+1]*Wrow[103] + msk[bb*3+2]*Wrow[104];
    return s;
}

// HINIT tile regions [h1b,_,1@157 | h0f,x,y,1 | h0b,x,y,1 | h1f] + CINIT.
// Replicates torch's (B,1200).view(8,B,150) on the row-major init buffer.
__global__ void k_init(const float* __restrict__ noise, const float* __restrict__ targ,
                       const float* __restrict__ msk,
                       const float* __restrict__ Wih, const float* __restrict__ bih,
                       const float* __restrict__ Wtk, const float* __restrict__ btk,
                       f16* __restrict__ hinit, float* __restrict__ cinitp) {
    int gid = blockIdx.x * 256 + threadIdx.x;   // 2048*1280 exact
    int b = gid / 1280, c = gid % 1280;
    if (c < 640) {
        int reg = c / 160, loc = c % 160;
        float v = 0.f;
        if (loc < 150) {
            int q = (reg == 0) ? 3 : (reg == 1) ? 0 : (reg == 2) ? 1 : 2; // h1b,h0f,h0b,h1f
            size_t i = (size_t)q * 2048 * 150 + (size_t)b * 150 + loc;
            int bb = (int)(i / 1200), rr = (int)(i % 1200);
            v = dot105(noise, targ, msk, Wih + (size_t)rr * 105, bb) + bih[rr];
        } else if (loc == 157) {
            if (reg != 3) v = 1.0f;             // bias column (b_l0/b_l1/b_proj)
        } else if (reg == 1 || reg == 2) {
            if (loc < 152) {                    // x0
                int o = loc - 150;
                v = dot105(noise, targ, msk, Wtk + o * 105, b) + btk[o];
            } else if (loc == 152) v = targ[b*2+0];   // y
            else if (loc == 153)   v = targ[b*2+1];
            else if (loc <= 156)   v = msk[b*3 + (loc - 154)];
        }
        hinit[(size_t)b * 640 + c] = (f16)v;
    } else {
        int idx = c - 640;                       // layer*320 + d*160 + j
        int layer = idx / 320, r = idx % 320, d = r / 160, j = r % 160;
        float v = 0.f;
        if (j < 150) {
            int q = 4 + layer * 2 + d;
            size_t i = (size_t)q * 2048 * 150 + (size_t)b * 150 + j;
            int bb = (int)(i / 1200), rr = (int)(i % 1200);
            v = dot105(noise, targ, msk, Wih + (size_t)rr * 105, bb) + bih[rr];
        }
        cinitp[(((size_t)layer * 2048 + b) * 2 + d) * 160 + j] = v;
    }
}

// Per-wave linear A-frag streams [16][100][512] + proj frags (10 nonzero ks).
__global__ void k_pack(const float* __restrict__ Wih0, const float* __restrict__ Whh0,
                       const float* __restrict__ bl0,
                       const float* __restrict__ Wih1, const float* __restrict__ Whh1,
                       const float* __restrict__ bl1,
                       const float* __restrict__ Wp,   const float* __restrict__ bpj,
                       f16* __restrict__ wstream, f16* __restrict__ pwpj) {
    int gid = blockIdx.x * 256 + threadIdx.x;   // 824,320 exact
    if (gid < 819200) {           // [w][100][64][8]
        int e = gid & 7, l = (gid >> 3) & 63;
        int f = (gid >> 9) % 100, w = gid / 51200;
        int r16 = l & 15, k8 = (l >> 4) * 8 + e;
        float v = 0.f;
        if (f < 25) {             // L0
            int ks = f / 5, m = f % 5;
            int mt = w * 5 + m, d = mt / 40, jt = mt % 40;
            int j = jt * 4 + (r16 >> 2), g = r16 & 3;
            int k = ks * 32 + k8;
            if (j < 150) {
                int R = d * 600 + g * 150 + j;
                if (k < 150)       v = Whh0[(size_t)R * 150 + k];
                else if (k < 157)  v = Wih0[(size_t)R * 7 + (k - 150)]; // x+y
                else if (k == 157) v = bl0[R];
            }
        } else {                  // L1
            int fc = f - 25, ks = fc / 5, m = fc % 5;
            int mt = w * 5 + m, d = mt / 40, jt = mt % 40;
            int j = jt * 4 + (r16 >> 2), g = r16 & 3;
            int k = ks * 32 + k8;
            if (j < 150) {
                int R = d * 600 + g * 150 + j;
                if (d == 0) {    // fwd: [h0f,x,y,1 | h0b,x,y,1 | h1f]
                    if (k < 150)                  v = Wih1[(size_t)R * 300 + k];
                    else if (k == 157)            v = bl1[R];
                    else if (k >= 160 && k < 310) v = Wih1[(size_t)R * 300 + (k - 10)];
                    else if (k >= 320 && k < 470) v = Whh1[(size_t)R * 150 + (k - 320)];
                } else {         // bwd: [h1b,_,1 | h0f,x,y,1 | h0b,x,y,1]
                    if (k < 150)                  v = Whh1[(size_t)R * 150 + k];
                    else if (k >= 160 && k < 310) v = Wih1[(size_t)R * 300 + (k - 160)];
                    else if (k == 317)            v = bl1[R];
                    else if (k >= 320 && k < 470) v = Wih1[(size_t)R * 300 + (k - 170)];
                }
            }
        }
        wstream[gid] = (f16)v;
    } else {                      // proj frags [10][64][8]: ks = ksi<5?ksi:ksi+10
        int pg = gid - 819200;
        int e = pg & 7, l = (pg >> 3) & 63, ksi = pg >> 9;
        int ks = ksi < 5 ? ksi : ksi + 10;
        int r16 = l & 15, k = ks * 32 + (l >> 4) * 8 + e;
        float v = 0.f;
        if (r16 < 2) {            // h1b 0..149 | bpj col 157 | h1f 480..629
            if (k < 150)                  v = Wp[r16 * 300 + 150 + k];
            else if (k == 157)            v = bpj[r16];
            else if (k >= 480 && k < 630) v = Wp[r16 * 300 + (k - 480)];
        }
        pwpj[pg] = (f16)v;
    }
}

// ---------------------------------------------------------------------------
// Main persistent kernel: 128 WGs x 1024 thr (16 waves), 16 batch rows/WG.
// Wave w owns M-tiles [5w,5w+5) (w<8 fwd, w>=8 bwd) x ONE N-tile.
// GEMM ks loops are RUNTIME loops (unroll 1): slot = m is compile-time
// (5-slot ring, 5 frags/ks), body ~25 instrs -> no spill possible.
// ---------------------------------------------------------------------------
__global__ __launch_bounds__(1024) void lstm_main(
    const f16* __restrict__ hinit, const float* __restrict__ cinit,
    const f16* __restrict__ wstream, const f16* __restrict__ pwpj,
    const int* __restrict__ lengths, float* __restrict__ out) {
    __shared__ f16 lds[56576];
    char* ldsb = (char*)lds;
    const int tid = threadIdx.x;
    const int w = tid >> 6, l = tid & 63;
    const int b0 = blockIdx.x * 16;
    const int l15 = l & 15, lg = l >> 4;
    const int dirw = w >> 3;

    // ---- stage LDS ----
    for (int it = tid; it < 16 * 80; it += 1024) {        // tile <- HINIT
        int row = it / 80, c8 = (it % 80) * 8;
        f16x8 v = *(const f16x8*)(hinit + (size_t)(b0 + row) * 640 + c8);
        int byte = row * 1312 + c8 * 2;  byte ^= (row & 7) << 4;
        *(f16x8*)(ldsb + byte) = v;
    }
    if (tid < 640)                                        // pjl (10 KB)
        *(f16x8*)(ldsb + 20992 + tid * 16) = *(const f16x8*)(pwpj + tid * 8);

    const int jb = ((w * 5) % 40) * 4 + lg;               // jj(m) = jb + 4m

    float c0s[5], c1s[5];
#pragma unroll
    for (int m = 0; m < 5; ++m) {
        int b = b0 + l15;
        c0s[m] = cinit[((size_t)b * 2 + dirw) * 160 + jb + 4 * m];
        c1s[m] = cinit[(((size_t)2048 + b) * 2 + dirw) * 160 + jb + 4 * m];
    }

    int lenb = 0;
    if (w == 0 && l < 16) lenb = lengths[b0 + l];

    const int baseL0 = 160 + dirw * 160;
    const int baseL1 = dirw ? 0 : 160;
    const int hw1    = dirw ? 0 : 480;
    const f16* wsrc = wstream + (size_t)w * 51200 + l * 8;
    char* ringb = ldsb + 31232 + w * 5120;

    // ring prologue: frags 0..4 (landed by the staging __syncthreads)
#pragma unroll
    for (int F = 0; F < 5; ++F) dma_frag(wsrc, ringb, F, F);

    __syncthreads();

#pragma unroll 1
    for (int t = 0; t < 128; ++t) {
        f32x4 acc[5];
        // ---- Phase A: L0 GEMM (K=160), frags 0..24 (runtime ks loop) ----
#pragma unroll
        for (int m = 0; m < 5; ++m) acc[m] = (f32x4){0.f, 0.f, 0.f, 0.f};
#pragma unroll 1
        for (int ks = 0; ks < 5; ++ks) {
            int byteb = l15 * 1312 + (baseL0 + ks * 32 + lg * 8) * 2;
            byteb ^= (l15 & 7) << 4;
            f16x8 bfr = *(const f16x8*)(ldsb + byteb);
#pragma unroll
            for (int m = 0; m < 5; ++m) {
                const int F = ks * 5 + m;                 // slot = F%5 = m
                waitv4();
                f16x8 a = *(const f16x8*)(ringb + m * 1024 + l * 16);
                waitlgkm0();                              // a + bfr in regs
                dma_frag(wsrc, ringb, F + 5, m);          // max 29 < 100
                acc[m] = __builtin_amdgcn_mfma_f32_16x16x32_f16(a, bfr, acc[m], 0, 0, 0);
            }
        }
        bar_lgkm();
        // ---- Phase B: act0 -> h0 into tile ----
#pragma unroll
        for (int m = 0; m < 5; ++m) {
            float gi = sigm_(acc[m][0]);
            float gf = sigm_(acc[m][1]);
            float gg = tanh_(acc[m][2]);
            float go = sigm_(acc[m][3]);
            float c = gf * c0s[m] + gi * gg;
            c0s[m] = c;
            float h = go * tanh_(c);
            if (jb + 4 * m < 150) {
                int byte = l15 * 1312 + (baseL0 + jb + 4 * m) * 2;  byte ^= (l15 & 7) << 4;
                *(f16*)(ldsb + byte) = (f16)h;
            }
        }
        bar_lgkm();
        // ---- Phase C: L1 GEMM (K=480), frags 25..99 (runtime ks loop) ----
#pragma unroll
        for (int m = 0; m < 5; ++m) acc[m] = (f32x4){0.f, 0.f, 0.f, 0.f};
#pragma unroll 1
        for (int ks = 0; ks < 15; ++ks) {
            int byteb = l15 * 1312 + (baseL1 + ks * 32 + lg * 8) * 2;
            byteb ^= (l15 & 7) << 4;
            f16x8 bfr = *(const f16x8*)(ldsb + byteb);
#pragma unroll
            for (int m = 0; m < 5; ++m) {
                const int F = 25 + ks * 5 + m;            // slot = m
                waitv4();
                f16x8 a = *(const f16x8*)(ringb + m * 1024 + l * 16);
                waitlgkm0();
                int fr = F + 5;                           // 30..104
                if (fr >= 100) fr -= 100;                 // wrap (last ks)
                dma_frag(wsrc, ringb, fr, m);
                acc[m] = __builtin_amdgcn_mfma_f32_16x16x32_f16(a, bfr, acc[m], 0, 0, 0);
            }
        }
        bar_lgkm();
        // ---- Phase D: act1 -> h1 into tile ----
#pragma unroll
        for (int m = 0; m < 5; ++m) {
            float gi = sigm_(acc[m][0]);
            float gf = sigm_(acc[m][1]);
            float gg = tanh_(acc[m][2]);
            float go = sigm_(acc[m][3]);
            float c = gf * c1s[m] + gi * gg;
            c1s[m] = c;
            float h = go * tanh_(c);
            if (jb + 4 * m < 150) {
                int byte = l15 * 1312 + (hw1 + jb + 4 * m) * 2;  byte ^= (l15 & 7) << 4;
                *(f16*)(ldsb + byte) = (f16)h;
            }
        }
        bar_lgkm();
        // ---- Phase E: proj (10 nonzero ks) + out + x writeback (wave 0) ----
        if (w == 0) {
            f32x4 ap = (f32x4){0.f, 0.f, 0.f, 0.f};
#pragma unroll
            for (int ksi = 0; ksi < 10; ++ksi) {
                int ks = ksi < 5 ? ksi : ksi + 10;
                int byte = l15 * 1312 + (ks * 32 + lg * 8) * 2;  byte ^= (l15 & 7) << 4;
                f16x8 bfp = *(const f16x8*)(ldsb + byte);
                f16x8 a = *(const f16x8*)(ldsb + 20992 + ksi * 1024 + l * 16);
                ap = __builtin_amdgcn_mfma_f32_16x16x32_f16(a, bfp, ap, 0, 0, 0);
            }
            if (l < 16) {
                float o0 = ap[0], o1 = ap[1];
                int b = b0 + l;
                bool live = (t < lenb);
                *(float2*)(out + ((size_t)b * 128 + t) * 2) =
                    make_float2(live ? o0 : 0.f, live ? o1 : 0.f);
                f16x2v xv = {(f16)o0, (f16)o1};
                int byte1 = l * 1312 + 620;  byte1 ^= (l & 7) << 4;   // h0f x
                *(f16x2v*)(ldsb + byte1) = xv;
                int byte2 = l * 1312 + 940;  byte2 ^= (l & 7) << 4;   // h0b x
                *(f16x2v*)(ldsb + byte2) = xv;
            }
        }
        bar_lgkm();
    }
}

extern "C" void kernel_launch(void* const* d_in, const int* in_sizes, int n_in,
                              void* d_out, int out_size, void* d_ws, size_t ws_size,
                              hipStream_t stream) {
    const float* noise = (const float*)d_in[0];
    const float* targ  = (const float*)d_in[1];
    const float* msk   = (const float*)d_in[2];
    const int*   lens  = (const int*)d_in[3];
    const float* Wih0  = (const float*)d_in[5];
    const float* Whh0  = (const float*)d_in[6];
    const float* bl0   = (const float*)d_in[7];
    const float* Wih1  = (const float*)d_in[8];
    const float* Whh1  = (const float*)d_in[9];
    const float* bl1   = (const float*)d_in[10];
    const float* Wp    = (const float*)d_in[11];
    const float* bpj   = (const float*)d_in[12];
    const float* Wit   = (const float*)d_in[13];
    const float* bit   = (const float*)d_in[14];
    const float* Wtk   = (const float*)d_in[15];
    const float* btk   = (const float*)d_in[16];

    char* ws = (char*)d_ws;
    f16*   HINIT = (f16*)(ws);
    float* CINIT = (float*)(ws + OFF_CINIT);
    f16*   WSTR  = (f16*)(ws + OFF_WSTR);
    f16*   PWPJ  = (f16*)(ws + OFF_PWPJ);

    hipLaunchKernelGGL(k_init,  dim3(10240), dim3(256), 0, stream,
                       noise, targ, msk, Wit, bit, Wtk, btk, HINIT, CINIT);
    hipLaunchKernelGGL(k_pack,  dim3(3220), dim3(256), 0, stream,
                       Wih0, Whh0, bl0, Wih1, Whh1, bl1, Wp, bpj, WSTR, PWPJ);
    hipLaunchKernelGGL(lstm_main, dim3(128), dim3(1024), 0, stream,
                       HINIT, CINIT, WSTR, PWPJ, lens, (float*)d_out);
}

// Round 19
// 2069.747 us; speedup vs baseline: 2.5397x; 1.0022x over previous
//
#include <hip/hip_runtime.h>

// ---------------------------------------------------------------------------
// 2-layer "bidirectional" LSTM generator, B=2048, T=128, HID=150.
// R19 = R18 (1.99 ms; spill-free runtime-ks loops, weights L2-resident:
// FETCH 6GB->10MB, WRITE 96MB->2KB) + 1-deep software pipeline of the ring
// reads to kill the remaining per-frag serialization:
//  - rotating `an` register: iteration m consumes aq=an (frag F, read last
//    iteration), reads an = slot (m+1)%5 (frag F+1, compile-time slot),
//    then refills slot m with frag F+5
//  - slot-reuse guard drops lgkmcnt(0) -> lgkmcnt(1) (slot m's read is >=2
//    LDS-ops old at the guard; only an(m) may remain outstanding)
//  - waitv(3) instead of waitv(4) (we read one frag ahead); wave-0's
//    Phase-E store adds one vmcnt token, count still safe
//  - an flows across phases AND steps (Phase C's last read = next step's
//    frag 0); init: read slot 0 after the staging __syncthreads
// Everything else identical to R18: 128 WGs x 1024 thr, 16 rows/WG, biases
// folded into weights, lgkm-only phase barriers, acc[5] AGPR, c in regs.
// LDS: tile 16x1312=20992 | pjl @20992 (10240) | rings @31232 + w*5120.
// ---------------------------------------------------------------------------

typedef _Float16 f16;
typedef _Float16 f16x8 __attribute__((ext_vector_type(8)));
typedef _Float16 f16x2v __attribute__((ext_vector_type(2)));
typedef float    f32x4 __attribute__((ext_vector_type(4)));

#define LOG2E 1.44269504f

__device__ __forceinline__ float sigm_(float x) {
    float e = __builtin_amdgcn_exp2f(-LOG2E * x);
    return __builtin_amdgcn_rcpf(1.f + e);
}
__device__ __forceinline__ float tanh_(float x) {
    float e = __builtin_amdgcn_exp2f(2.f * LOG2E * x);
    return 1.f - 2.f * __builtin_amdgcn_rcpf(1.f + e);
}

// vmcnt(3): all but 3 newest VMEM ops complete -> frag F+1's DMA landed
__device__ __forceinline__ void waitv3() {
    __builtin_amdgcn_s_waitcnt(0x0F73);
    __builtin_amdgcn_sched_barrier(0);
}
// lgkmcnt(1): all but the newest LDS op retired -> slot-m's read retired
__device__ __forceinline__ void waitlgkm1() {
    __builtin_amdgcn_s_waitcnt(0xC17F);
    __builtin_amdgcn_sched_barrier(0);
}
__device__ __forceinline__ void bar_lgkm() {
    asm volatile("s_waitcnt lgkmcnt(0)" ::: "memory");
    __builtin_amdgcn_s_barrier();
    asm volatile("" ::: "memory");
}

typedef const __attribute__((address_space(1))) void* gas_t;
typedef __attribute__((address_space(3))) void* las_t;

__device__ __forceinline__ void dma_frag(const f16* wsrc, char* ringb, int F, int slot) {
    __builtin_amdgcn_global_load_lds((gas_t)(wsrc + (size_t)F * 512),
                                     (las_t)(ringb + slot * 1024), 16, 0, 0);
}

// ---------------- ws layout (bytes) ----------------
#define OFF_CINIT 2621440
#define OFF_WSTR  7864320
#define OFF_PWPJ  9502720

__device__ float dot105(const float* __restrict__ noise,
                        const float* __restrict__ targ,
                        const float* __restrict__ msk,
                        const float* __restrict__ Wrow, int bb) {
    float s = 0.f;
    const float* nz = noise + (size_t)bb * 100;
#pragma unroll 4
    for (int k = 0; k < 100; ++k) s += nz[k] * Wrow[k];
    s += targ[bb*2+0]*Wrow[100] + targ[bb*2+1]*Wrow[101];
    s += msk[bb*3+0]*Wrow[102] + msk[bb*3+1]*Wrow[103] + msk[bb*3+2]*Wrow[104];
    return s;
}

// HINIT tile regions [h1b,_,1@157 | h0f,x,y,1 | h0b,x,y,1 | h1f] + CINIT.
// Replicates torch's (B,1200).view(8,B,150) on the row-major init buffer.
__global__ void k_init(const float* __restrict__ noise, const float* __restrict__ targ,
                       const float* __restrict__ msk,
                       const float* __restrict__ Wih, const float* __restrict__ bih,
                       const float* __restrict__ Wtk, const float* __restrict__ btk,
                       f16* __restrict__ hinit, float* __restrict__ cinitp) {
    int gid = blockIdx.x * 256 + threadIdx.x;   // 2048*1280 exact
    int b = gid / 1280, c = gid % 1280;
    if (c < 640) {
        int reg = c / 160, loc = c % 160;
        float v = 0.f;
        if (loc < 150) {
            int q = (reg == 0) ? 3 : (reg == 1) ? 0 : (reg == 2) ? 1 : 2; // h1b,h0f,h0b,h1f
            size_t i = (size_t)q * 2048 * 150 + (size_t)b * 150 + loc;
            int bb = (int)(i / 1200), rr = (int)(i % 1200);
            v = dot105(noise, targ, msk, Wih + (size_t)rr * 105, bb) + bih[rr];
        } else if (loc == 157) {
            if (reg != 3) v = 1.0f;             // bias column (b_l0/b_l1/b_proj)
        } else if (reg == 1 || reg == 2) {
            if (loc < 152) {                    // x0
                int o = loc - 150;
                v = dot105(noise, targ, msk, Wtk + o * 105, b) + btk[o];
            } else if (loc == 152) v = targ[b*2+0];   // y
            else if (loc == 153)   v = targ[b*2+1];
            else if (loc <= 156)   v = msk[b*3 + (loc - 154)];
        }
        hinit[(size_t)b * 640 + c] = (f16)v;
    } else {
        int idx = c - 640;                       // layer*320 + d*160 + j
        int layer = idx / 320, r = idx % 320, d = r / 160, j = r % 160;
        float v = 0.f;
        if (j < 150) {
            int q = 4 + layer * 2 + d;
            size_t i = (size_t)q * 2048 * 150 + (size_t)b * 150 + j;
            int bb = (int)(i / 1200), rr = (int)(i % 1200);
            v = dot105(noise, targ, msk, Wih + (size_t)rr * 105, bb) + bih[rr];
        }
        cinitp[(((size_t)layer * 2048 + b) * 2 + d) * 160 + j] = v;
    }
}

// Per-wave linear A-frag streams [16][100][512] + proj frags (10 nonzero ks).
__global__ void k_pack(const float* __restrict__ Wih0, const float* __restrict__ Whh0,
                       const float* __restrict__ bl0,
                       const float* __restrict__ Wih1, const float* __restrict__ Whh1,
                       const float* __restrict__ bl1,
                       const float* __restrict__ Wp,   const float* __restrict__ bpj,
                       f16* __restrict__ wstream, f16* __restrict__ pwpj) {
    int gid = blockIdx.x * 256 + threadIdx.x;   // 824,320 exact
    if (gid < 819200) {           // [w][100][64][8]
        int e = gid & 7, l = (gid >> 3) & 63;
        int f = (gid >> 9) % 100, w = gid / 51200;
        int r16 = l & 15, k8 = (l >> 4) * 8 + e;
        float v = 0.f;
        if (f < 25) {             // L0
            int ks = f / 5, m = f % 5;
            int mt = w * 5 + m, d = mt / 40, jt = mt % 40;
            int j = jt * 4 + (r16 >> 2), g = r16 & 3;
            int k = ks * 32 + k8;
            if (j < 150) {
                int R = d * 600 + g * 150 + j;
                if (k < 150)       v = Whh0[(size_t)R * 150 + k];
                else if (k < 157)  v = Wih0[(size_t)R * 7 + (k - 150)]; // x+y
                else if (k == 157) v = bl0[R];
            }
        } else {                  // L1
            int fc = f - 25, ks = fc / 5, m = fc % 5;
            int mt = w * 5 + m, d = mt / 40, jt = mt % 40;
            int j = jt * 4 + (r16 >> 2), g = r16 & 3;
            int k = ks * 32 + k8;
            if (j < 150) {
                int R = d * 600 + g * 150 + j;
                if (d == 0) {    // fwd: [h0f,x,y,1 | h0b,x,y,1 | h1f]
                    if (k < 150)                  v = Wih1[(size_t)R * 300 + k];
                    else if (k == 157)            v = bl1[R];
                    else if (k >= 160 && k < 310) v = Wih1[(size_t)R * 300 + (k - 10)];
                    else if (k >= 320 && k < 470) v = Whh1[(size_t)R * 150 + (k - 320)];
                } else {         // bwd: [h1b,_,1 | h0f,x,y,1 | h0b,x,y,1]
                    if (k < 150)                  v = Whh1[(size_t)R * 150 + k];
                    else if (k >= 160 && k < 310) v = Wih1[(size_t)R * 300 + (k - 160)];
                    else if (k == 317)            v = bl1[R];
                    else if (k >= 320 && k < 470) v = Wih1[(size_t)R * 300 + (k - 170)];
                }
            }
        }
        wstream[gid] = (f16)v;
    } else {                      // proj frags [10][64][8]: ks = ksi<5?ksi:ksi+10
        int pg = gid - 819200;
        int e = pg & 7, l = (pg >> 3) & 63, ksi = pg >> 9;
        int ks = ksi < 5 ? ksi : ksi + 10;
        int r16 = l & 15, k = ks * 32 + (l >> 4) * 8 + e;
        float v = 0.f;
        if (r16 < 2) {            // h1b 0..149 | bpj col 157 | h1f 480..629
            if (k < 150)                  v = Wp[r16 * 300 + 150 + k];
            else if (k == 157)            v = bpj[r16];
            else if (k >= 480 && k < 630) v = Wp[r16 * 300 + (k - 480)];
        }
        pwpj[pg] = (f16)v;
    }
}

// ---------------------------------------------------------------------------
// Main persistent kernel: 128 WGs x 1024 thr (16 waves), 16 batch rows/WG.
// Wave w owns M-tiles [5w,5w+5) (w<8 fwd, w>=8 bwd) x ONE N-tile.
// ---------------------------------------------------------------------------
__global__ __launch_bounds__(1024) void lstm_main(
    const f16* __restrict__ hinit, const float* __restrict__ cinit,
    const f16* __restrict__ wstream, const f16* __restrict__ pwpj,
    const int* __restrict__ lengths, float* __restrict__ out) {
    __shared__ f16 lds[56576];
    char* ldsb = (char*)lds;
    const int tid = threadIdx.x;
    const int w = tid >> 6, l = tid & 63;
    const int b0 = blockIdx.x * 16;
    const int l15 = l & 15, lg = l >> 4;
    const int dirw = w >> 3;

    // ---- stage LDS ----
    for (int it = tid; it < 16 * 80; it += 1024) {        // tile <- HINIT
        int row = it / 80, c8 = (it % 80) * 8;
        f16x8 v = *(const f16x8*)(hinit + (size_t)(b0 + row) * 640 + c8);
        int byte = row * 1312 + c8 * 2;  byte ^= (row & 7) << 4;
        *(f16x8*)(ldsb + byte) = v;
    }
    if (tid < 640)                                        // pjl (10 KB)
        *(f16x8*)(ldsb + 20992 + tid * 16) = *(const f16x8*)(pwpj + tid * 8);

    const int jb = ((w * 5) % 40) * 4 + lg;               // jj(m) = jb + 4m

    float c0s[5], c1s[5];
#pragma unroll
    for (int m = 0; m < 5; ++m) {
        int b = b0 + l15;
        c0s[m] = cinit[((size_t)b * 2 + dirw) * 160 + jb + 4 * m];
        c1s[m] = cinit[(((size_t)2048 + b) * 2 + dirw) * 160 + jb + 4 * m];
    }

    int lenb = 0;
    if (w == 0 && l < 16) lenb = lengths[b0 + l];

    const int baseL0 = 160 + dirw * 160;
    const int baseL1 = dirw ? 0 : 160;
    const int hw1    = dirw ? 0 : 480;
    const f16* wsrc = wstream + (size_t)w * 51200 + l * 8;
    char* ringb = ldsb + 31232 + w * 5120;

    // ring prologue: frags 0..4 (landed by the staging __syncthreads)
#pragma unroll
    for (int F = 0; F < 5; ++F) dma_frag(wsrc, ringb, F, F);

    __syncthreads();

    // pipeline prologue: an holds frag 0 (all DMAs drained by syncthreads)
    f16x8 an = *(const f16x8*)(ringb + 0 * 1024 + l * 16);

#pragma unroll 1
    for (int t = 0; t < 128; ++t) {
        f32x4 acc[5];
        // ---- Phase A: L0 GEMM (K=160), frags 0..24 ----
#pragma unroll
        for (int m = 0; m < 5; ++m) acc[m] = (f32x4){0.f, 0.f, 0.f, 0.f};
#pragma unroll 1
        for (int ks = 0; ks < 5; ++ks) {
            int byteb = l15 * 1312 + (baseL0 + ks * 32 + lg * 8) * 2;
            byteb ^= (l15 & 7) << 4;
            f16x8 bfr = *(const f16x8*)(ldsb + byteb);
#pragma unroll
            for (int m = 0; m < 5; ++m) {
                const int F = ks * 5 + m;                 // consuming frag F
                f16x8 aq = an;
                waitv3();                                 // frag F+1 landed
                an = *(const f16x8*)(ringb + ((m + 1) % 5) * 1024 + l * 16);
                waitlgkm1();                              // slot-m read retired
                dma_frag(wsrc, ringb, F + 5, m);          // max 29 < 100
                acc[m] = __builtin_amdgcn_mfma_f32_16x16x32_f16(aq, bfr, acc[m], 0, 0, 0);
            }
        }
        bar_lgkm();
        // ---- Phase B: act0 -> h0 into tile ----
#pragma unroll
        for (int m = 0; m < 5; ++m) {
            float gi = sigm_(acc[m][0]);
            float gf = sigm_(acc[m][1]);
            float gg = tanh_(acc[m][2]);
            float go = sigm_(acc[m][3]);
            float c = gf * c0s[m] + gi * gg;
            c0s[m] = c;
            float h = go * tanh_(c);
            if (jb + 4 * m < 150) {
                int byte = l15 * 1312 + (baseL0 + jb + 4 * m) * 2;  byte ^= (l15 & 7) << 4;
                *(f16*)(ldsb + byte) = (f16)h;
            }
        }
        bar_lgkm();
        // ---- Phase C: L1 GEMM (K=480), frags 25..99 ----
#pragma unroll
        for (int m = 0; m < 5; ++m) acc[m] = (f32x4){0.f, 0.f, 0.f, 0.f};
#pragma unroll 1
        for (int ks = 0; ks < 15; ++ks) {
            int byteb = l15 * 1312 + (baseL1 + ks * 32 + lg * 8) * 2;
            byteb ^= (l15 & 7) << 4;
            f16x8 bfr = *(const f16x8*)(ldsb + byteb);
#pragma unroll
            for (int m = 0; m < 5; ++m) {
                const int F = 25 + ks * 5 + m;            // slot = m
                f16x8 aq = an;
                waitv3();
                an = *(const f16x8*)(ringb + ((m + 1) % 5) * 1024 + l * 16);
                waitlgkm1();
                int fr = F + 5;                           // 30..104
                if (fr >= 100) fr -= 100;                 // wrap (last ks)
                dma_frag(wsrc, ringb, fr, m);
                acc[m] = __builtin_amdgcn_mfma_f32_16x16x32_f16(aq, bfr, acc[m], 0, 0, 0);
            }
        }
        bar_lgkm();
        // ---- Phase D: act1 -> h1 into tile ----
#pragma unroll
        for (int m = 0; m < 5; ++m) {
            float gi = sigm_(acc[m][0]);
            float gf = sigm_(acc[m][1]);
            float gg = tanh_(acc[m][2]);
            float go = sigm_(acc[m][3]);
            float c = gf * c1s[m] + gi * gg;
            c1s[m] = c;
            float h = go * tanh_(c);
            if (jb + 4 * m < 150) {
                int byte = l15 * 1312 + (hw1 + jb + 4 * m) * 2;  byte ^= (l15 & 7) << 4;
                *(f16*)(ldsb + byte) = (f16)h;
            }
        }
        bar_lgkm();
        // ---- Phase E: proj (10 nonzero ks) + out + x writeback (wave 0) ----
        if (w == 0) {
            f32x4 ap = (f32x4){0.f, 0.f, 0.f, 0.f};
#pragma unroll
            for (int ksi = 0; ksi < 10; ++ksi) {
                int ks = ksi < 5 ? ksi : ksi + 10;
                int byte = l15 * 1312 + (ks * 32 + lg * 8) * 2;  byte ^= (l15 & 7) << 4;
                f16x8 bfp = *(const f16x8*)(ldsb + byte);
                f16x8 a = *(const f16x8*)(ldsb + 20992 + ksi * 1024 + l * 16);
                ap = __builtin_amdgcn_mfma_f32_16x16x32_f16(a, bfp, ap, 0, 0, 0);
            }
            if (l < 16) {
                float o0 = ap[0], o1 = ap[1];
                int b = b0 + l;
                bool live = (t < lenb);
                *(float2*)(out + ((size_t)b * 128 + t) * 2) =
                    make_float2(live ? o0 : 0.f, live ? o1 : 0.f);
                f16x2v xv = {(f16)o0, (f16)o1};
                int byte1 = l * 1312 + 620;  byte1 ^= (l & 7) << 4;   // h0f x
                *(f16x2v*)(ldsb + byte1) = xv;
                int byte2 = l * 1312 + 940;  byte2 ^= (l & 7) << 4;   // h0b x
                *(f16x2v*)(ldsb + byte2) = xv;
            }
        }
        bar_lgkm();
    }
}

extern "C" void kernel_launch(void* const* d_in, const int* in_sizes, int n_in,
                              void* d_out, int out_size, void* d_ws, size_t ws_size,
                              hipStream_t stream) {
    const float* noise = (const float*)d_in[0];
    const float* targ  = (const float*)d_in[1];
    const float* msk   = (const float*)d_in[2];
    const int*   lens  = (const int*)d_in[3];
    const float* Wih0  = (const float*)d_in[5];
    const float* Whh0  = (const float*)d_in[6];
    const float* bl0   = (const float*)d_in[7];
    const float* Wih1  = (const float*)d_in[8];
    const float* Whh1  = (const float*)d_in[9];
    const float* bl1   = (const float*)d_in[10];
    const float* Wp    = (const float*)d_in[11];
    const float* bpj   = (const float*)d_in[12];
    const float* Wit   = (const float*)d_in[13];
    const float* bit   = (const float*)d_in[14];
    const float* Wtk   = (const float*)d_in[15];
    const float* btk   = (const float*)d_in[16];

    char* ws = (char*)d_ws;
    f16*   HINIT = (f16*)(ws);
    float* CINIT = (float*)(ws + OFF_CINIT);
    f16*   WSTR  = (f16*)(ws + OFF_WSTR);
    f16*   PWPJ  = (f16*)(ws + OFF_PWPJ);

    hipLaunchKernelGGL(k_init,  dim3(10240), dim3(256), 0, stream,
                       noise, targ, msk, Wit, bit, Wtk, btk, HINIT, CINIT);
    hipLaunchKernelGGL(k_pack,  dim3(3220), dim3(256), 0, stream,
                       Wih0, Whh0, bl0, Wih1, Whh1, bl1, Wp, bpj, WSTR, PWPJ);
    hipLaunchKernelGGL(lstm_main, dim3(128), dim3(1024), 0, stream,
                       HINIT, CINIT, WSTR, PWPJ, lens, (float*)d_out);
}

// Round 20
// 2034.051 us; speedup vs baseline: 2.5843x; 1.0175x over previous
//
#include <hip/hip_runtime.h>

// ---------------------------------------------------------------------------
// 2-layer "bidirectional" LSTM generator, B=2048, T=128, HID=150.
// R20 = R18 (1.97 ms) with the weight path moved LDS -> REGISTER ring.
// R18/R19 counters put the kernel at the LDS-pipe roofline: weights crossed
// LDS twice (DMA write + ds_read, 3.2 MB/CU/step) ~= 27-41K cyc == measured
// 37K cyc/step. Register ring eliminates LDS weight traffic entirely:
//   ring[5] f16x8 (20 VGPR), slot = m compile-time (inner m-loop unrolled,
//   runtime ks loops keep the body tiny -> no spill, R18-proven),
//   per frag: aq = ring[m]; ring[m] = global_load(F+5); mfma(aq,bfr,acc).
// No manual waitcnt: compiler's in-order vmcnt discipline inserts vmcnt(4)
// before each consume. lgkm-only phase barriers (tile h coherence).
// 128 WGs x 1024 thr (16 waves), 16 batch rows/WG, biases folded into
// weights, acc[5] AGPR, c-state in regs.
// LDS: tile 16x1312=20992 | pjl @20992 (10240). Total 31232 B.
// ---------------------------------------------------------------------------

typedef _Float16 f16;
typedef _Float16 f16x8 __attribute__((ext_vector_type(8)));
typedef _Float16 f16x2v __attribute__((ext_vector_type(2)));
typedef float    f32x4 __attribute__((ext_vector_type(4)));

#define LOG2E 1.44269504f

__device__ __forceinline__ float sigm_(float x) {
    float e = __builtin_amdgcn_exp2f(-LOG2E * x);
    return __builtin_amdgcn_rcpf(1.f + e);
}
__device__ __forceinline__ float tanh_(float x) {
    float e = __builtin_amdgcn_exp2f(2.f * LOG2E * x);
    return 1.f - 2.f * __builtin_amdgcn_rcpf(1.f + e);
}

// Phase barrier: drain LDS ops only (tile h coherence); register loads from
// global memory stay in flight (consumers are compiler-tracked via vmcnt).
__device__ __forceinline__ void bar_lgkm() {
    asm volatile("s_waitcnt lgkmcnt(0)" ::: "memory");
    __builtin_amdgcn_s_barrier();
    asm volatile("" ::: "memory");
}

// ---------------- ws layout (bytes) ----------------
#define OFF_CINIT 2621440
#define OFF_WSTR  7864320
#define OFF_PWPJ  9502720

__device__ float dot105(const float* __restrict__ noise,
                        const float* __restrict__ targ,
                        const float* __restrict__ msk,
                        const float* __restrict__ Wrow, int bb) {
    float s = 0.f;
    const float* nz = noise + (size_t)bb * 100;
#pragma unroll 4
    for (int k = 0; k < 100; ++k) s += nz[k] * Wrow[k];
    s += targ[bb*2+0]*Wrow[100] + targ[bb*2+1]*Wrow[101];
    s += msk[bb*3+0]*Wrow[102] + msk[bb*3+1]*Wrow[103] + msk[bb*3+2]*Wrow[104];
    return s;
}

// HINIT tile regions [h1b,_,1@157 | h0f,x,y,1 | h0b,x,y,1 | h1f] + CINIT.
// Replicates torch's (B,1200).view(8,B,150) on the row-major init buffer.
__global__ void k_init(const float* __restrict__ noise, const float* __restrict__ targ,
                       const float* __restrict__ msk,
                       const float* __restrict__ Wih, const float* __restrict__ bih,
                       const float* __restrict__ Wtk, const float* __restrict__ btk,
                       f16* __restrict__ hinit, float* __restrict__ cinitp) {
    int gid = blockIdx.x * 256 + threadIdx.x;   // 2048*1280 exact
    int b = gid / 1280, c = gid % 1280;
    if (c < 640) {
        int reg = c / 160, loc = c % 160;
        float v = 0.f;
        if (loc < 150) {
            int q = (reg == 0) ? 3 : (reg == 1) ? 0 : (reg == 2) ? 1 : 2; // h1b,h0f,h0b,h1f
            size_t i = (size_t)q * 2048 * 150 + (size_t)b * 150 + loc;
            int bb = (int)(i / 1200), rr = (int)(i % 1200);
            v = dot105(noise, targ, msk, Wih + (size_t)rr * 105, bb) + bih[rr];
        } else if (loc == 157) {
            if (reg != 3) v = 1.0f;             // bias column (b_l0/b_l1/b_proj)
        } else if (reg == 1 || reg == 2) {
            if (loc < 152) {                    // x0
                int o = loc - 150;
                v = dot105(noise, targ, msk, Wtk + o * 105, b) + btk[o];
            } else if (loc == 152) v = targ[b*2+0];   // y
            else if (loc == 153)   v = targ[b*2+1];
            else if (loc <= 156)   v = msk[b*3 + (loc - 154)];
        }
        hinit[(size_t)b * 640 + c] = (f16)v;
    } else {
        int idx = c - 640;                       // layer*320 + d*160 + j
        int layer = idx / 320, r = idx % 320, d = r / 160, j = r % 160;
        float v = 0.f;
        if (j < 150) {
            int q = 4 + layer * 2 + d;
            size_t i = (size_t)q * 2048 * 150 + (size_t)b * 150 + j;
            int bb = (int)(i / 1200), rr = (int)(i % 1200);
            v = dot105(noise, targ, msk, Wih + (size_t)rr * 105, bb) + bih[rr];
        }
        cinitp[(((size_t)layer * 2048 + b) * 2 + d) * 160 + j] = v;
    }
}

// Per-wave linear A-frag streams [16][100][512] + proj frags (10 nonzero ks).
__global__ void k_pack(const float* __restrict__ Wih0, const float* __restrict__ Whh0,
                       const float* __restrict__ bl0,
                       const float* __restrict__ Wih1, const float* __restrict__ Whh1,
                       const float* __restrict__ bl1,
                       const float* __restrict__ Wp,   const float* __restrict__ bpj,
                       f16* __restrict__ wstream, f16* __restrict__ pwpj) {
    int gid = blockIdx.x * 256 + threadIdx.x;   // 824,320 exact
    if (gid < 819200) {           // [w][100][64][8]
        int e = gid & 7, l = (gid >> 3) & 63;
        int f = (gid >> 9) % 100, w = gid / 51200;
        int r16 = l & 15, k8 = (l >> 4) * 8 + e;
        float v = 0.f;
        if (f < 25) {             // L0
            int ks = f / 5, m = f % 5;
            int mt = w * 5 + m, d = mt / 40, jt = mt % 40;
            int j = jt * 4 + (r16 >> 2), g = r16 & 3;
            int k = ks * 32 + k8;
            if (j < 150) {
                int R = d * 600 + g * 150 + j;
                if (k < 150)       v = Whh0[(size_t)R * 150 + k];
                else if (k < 157)  v = Wih0[(size_t)R * 7 + (k - 150)]; // x+y
                else if (k == 157) v = bl0[R];
            }
        } else {                  // L1
            int fc = f - 25, ks = fc / 5, m = fc % 5;
            int mt = w * 5 + m, d = mt / 40, jt = mt % 40;
            int j = jt * 4 + (r16 >> 2), g = r16 & 3;
            int k = ks * 32 + k8;
            if (j < 150) {
                int R = d * 600 + g * 150 + j;
                if (d == 0) {    // fwd: [h0f,x,y,1 | h0b,x,y,1 | h1f]
                    if (k < 150)                  v = Wih1[(size_t)R * 300 + k];
                    else if (k == 157)            v = bl1[R];
                    else if (k >= 160 && k < 310) v = Wih1[(size_t)R * 300 + (k - 10)];
                    else if (k >= 320 && k < 470) v = Whh1[(size_t)R * 150 + (k - 320)];
                } else {         // bwd: [h1b,_,1 | h0f,x,y,1 | h0b,x,y,1]
                    if (k < 150)                  v = Whh1[(size_t)R * 150 + k];
                    else if (k >= 160 && k < 310) v = Wih1[(size_t)R * 300 + (k - 160)];
                    else if (k == 317)            v = bl1[R];
                    else if (k >= 320 && k < 470) v = Wih1[(size_t)R * 300 + (k - 170)];
                }
            }
        }
        wstream[gid] = (f16)v;
    } else {                      // proj frags [10][64][8]: ks = ksi<5?ksi:ksi+10
        int pg = gid - 819200;
        int e = pg & 7, l = (pg >> 3) & 63, ksi = pg >> 9;
        int ks = ksi < 5 ? ksi : ksi + 10;
        int r16 = l & 15, k = ks * 32 + (l >> 4) * 8 + e;
        float v = 0.f;
        if (r16 < 2) {            // h1b 0..149 | bpj col 157 | h1f 480..629
            if (k < 150)                  v = Wp[r16 * 300 + 150 + k];
            else if (k == 157)            v = bpj[r16];
            else if (k >= 480 && k < 630) v = Wp[r16 * 300 + (k - 480)];
        }
        pwpj[pg] = (f16)v;
    }
}

// ---------------------------------------------------------------------------
// Main persistent kernel: 128 WGs x 1024 thr (16 waves), 16 batch rows/WG.
// Wave w owns M-tiles [5w,5w+5) (w<8 fwd, w>=8 bwd) x ONE N-tile.
// Weights stream global -> register ring[5] (no LDS leg).
// ---------------------------------------------------------------------------
__global__ __launch_bounds__(1024) void lstm_main(
    const f16* __restrict__ hinit, const float* __restrict__ cinit,
    const f16* __restrict__ wstream, const f16* __restrict__ pwpj,
    const int* __restrict__ lengths, float* __restrict__ out) {
    __shared__ f16 lds[15616];
    char* ldsb = (char*)lds;
    const int tid = threadIdx.x;
    const int w = tid >> 6, l = tid & 63;
    const int b0 = blockIdx.x * 16;
    const int l15 = l & 15, lg = l >> 4;
    const int dirw = w >> 3;

    // ---- stage LDS ----
    for (int it = tid; it < 16 * 80; it += 1024) {        // tile <- HINIT
        int row = it / 80, c8 = (it % 80) * 8;
        f16x8 v = *(const f16x8*)(hinit + (size_t)(b0 + row) * 640 + c8);
        int byte = row * 1312 + c8 * 2;  byte ^= (row & 7) << 4;
        *(f16x8*)(ldsb + byte) = v;
    }
    if (tid < 640)                                        // pjl (10 KB)
        *(f16x8*)(ldsb + 20992 + tid * 16) = *(const f16x8*)(pwpj + tid * 8);

    const int jb = ((w * 5) % 40) * 4 + lg;               // jj(m) = jb + 4m

    float c0s[5], c1s[5];
#pragma unroll
    for (int m = 0; m < 5; ++m) {
        int b = b0 + l15;
        c0s[m] = cinit[((size_t)b * 2 + dirw) * 160 + jb + 4 * m];
        c1s[m] = cinit[(((size_t)2048 + b) * 2 + dirw) * 160 + jb + 4 * m];
    }

    int lenb = 0;
    if (w == 0 && l < 16) lenb = lengths[b0 + l];

    const int baseL0 = 160 + dirw * 160;
    const int baseL1 = dirw ? 0 : 160;
    const int hw1    = dirw ? 0 : 480;
    const f16* wsrc = wstream + (size_t)w * 51200 + l * 8;

    // register ring prologue: frags 0..4
    f16x8 ring[5];
#pragma unroll
    for (int i = 0; i < 5; ++i) ring[i] = *(const f16x8*)(wsrc + (size_t)i * 512);

    __syncthreads();

#pragma unroll 1
    for (int t = 0; t < 128; ++t) {
        f32x4 acc[5];
        // ---- Phase A: L0 GEMM (K=160), frags 0..24 (runtime ks loop) ----
#pragma unroll
        for (int m = 0; m < 5; ++m) acc[m] = (f32x4){0.f, 0.f, 0.f, 0.f};
#pragma unroll 1
        for (int ks = 0; ks < 5; ++ks) {
            int byteb = l15 * 1312 + (baseL0 + ks * 32 + lg * 8) * 2;
            byteb ^= (l15 & 7) << 4;
            f16x8 bfr = *(const f16x8*)(ldsb + byteb);
#pragma unroll
            for (int m = 0; m < 5; ++m) {
                const int F = ks * 5 + m;                 // slot = F%5 = m
                f16x8 aq = ring[m];
                ring[m] = *(const f16x8*)(wsrc + (size_t)(F + 5) * 512); // max 29
                acc[m] = __builtin_amdgcn_mfma_f32_16x16x32_f16(aq, bfr, acc[m], 0, 0, 0);
            }
        }
        bar_lgkm();
        // ---- Phase B: act0 -> h0 into tile ----
#pragma unroll
        for (int m = 0; m < 5; ++m) {
            float gi = sigm_(acc[m][0]);
            float gf = sigm_(acc[m][1]);
            float gg = tanh_(acc[m][2]);
            float go = sigm_(acc[m][3]);
            float c = gf * c0s[m] + gi * gg;
            c0s[m] = c;
            float h = go * tanh_(c);
            if (jb + 4 * m < 150) {
                int byte = l15 * 1312 + (baseL0 + jb + 4 * m) * 2;  byte ^= (l15 & 7) << 4;
                *(f16*)(ldsb + byte) = (f16)h;
            }
        }
        bar_lgkm();
        // ---- Phase C: L1 GEMM (K=480), frags 25..99 (runtime ks loop) ----
#pragma unroll
        for (int m = 0; m < 5; ++m) acc[m] = (f32x4){0.f, 0.f, 0.f, 0.f};
#pragma unroll 1
        for (int ks = 0; ks < 15; ++ks) {
            int byteb = l15 * 1312 + (baseL1 + ks * 32 + lg * 8) * 2;
            byteb ^= (l15 & 7) << 4;
            f16x8 bfr = *(const f16x8*)(ldsb + byteb);
            int frb = 30 + ks * 5;                        // refill base
            if (frb >= 100) frb -= 100;                   // last ks wraps to 0
#pragma unroll
            for (int m = 0; m < 5; ++m) {
                f16x8 aq = ring[m];
                ring[m] = *(const f16x8*)(wsrc + (size_t)(frb + m) * 512);
                acc[m] = __builtin_amdgcn_mfma_f32_16x16x32_f16(aq, bfr, acc[m], 0, 0, 0);
            }
        }
        bar_lgkm();
        // ---- Phase D: act1 -> h1 into tile ----
#pragma unroll
        for (int m = 0; m < 5; ++m) {
            float gi = sigm_(acc[m][0]);
            float gf = sigm_(acc[m][1]);
            float gg = tanh_(acc[m][2]);
            float go = sigm_(acc[m][3]);
            float c = gf * c1s[m] + gi * gg;
            c1s[m] = c;
            float h = go * tanh_(c);
            if (jb + 4 * m < 150) {
                int byte = l15 * 1312 + (hw1 + jb + 4 * m) * 2;  byte ^= (l15 & 7) << 4;
                *(f16*)(ldsb + byte) = (f16)h;
            }
        }
        bar_lgkm();
        // ---- Phase E: proj (10 nonzero ks) + out + x writeback (wave 0) ----
        if (w == 0) {
            f32x4 ap = (f32x4){0.f, 0.f, 0.f, 0.f};
#pragma unroll
            for (int ksi = 0; ksi < 10; ++ksi) {
                int ks = ksi < 5 ? ksi : ksi + 10;
                int byte = l15 * 1312 + (ks * 32 + lg * 8) * 2;  byte ^= (l15 & 7) << 4;
                f16x8 bfp = *(const f16x8*)(ldsb + byte);
                f16x8 a = *(const f16x8*)(ldsb + 20992 + ksi * 1024 + l * 16);
                ap = __builtin_amdgcn_mfma_f32_16x16x32_f16(a, bfp, ap, 0, 0, 0);
            }
            if (l < 16) {
                float o0 = ap[0], o1 = ap[1];
                int b = b0 + l;
                bool live = (t < lenb);
                *(float2*)(out + ((size_t)b * 128 + t) * 2) =
                    make_float2(live ? o0 : 0.f, live ? o1 : 0.f);
                f16x2v xv = {(f16)o0, (f16)o1};
                int byte1 = l * 1312 + 620;  byte1 ^= (l & 7) << 4;   // h0f x
                *(f16x2v*)(ldsb + byte1) = xv;
                int byte2 = l * 1312 + 940;  byte2 ^= (l & 7) << 4;   // h0b x
                *(f16x2v*)(ldsb + byte2) = xv;
            }
        }
        bar_lgkm();
    }
}

extern "C" void kernel_launch(void* const* d_in, const int* in_sizes, int n_in,
                              void* d_out, int out_size, void* d_ws, size_t ws_size,
                              hipStream_t stream) {
    const float* noise = (const float*)d_in[0];
    const float* targ  = (const float*)d_in[1];
    const float* msk   = (const float*)d_in[2];
    const int*   lens  = (const int*)d_in[3];
    const float* Wih0  = (const float*)d_in[5];
    const float* Whh0  = (const float*)d_in[6];
    const float* bl0   = (const float*)d_in[7];
    const float* Wih1  = (const float*)d_in[8];
    const float* Whh1  = (const float*)d_in[9];
    const float* bl1   = (const float*)d_in[10];
    const float* Wp    = (const float*)d_in[11];
    const float* bpj   = (const float*)d_in[12];
    const float* Wit   = (const float*)d_in[13];
    const float* bit   = (const float*)d_in[14];
    const float* Wtk   = (const float*)d_in[15];
    const float* btk   = (const float*)d_in[16];

    char* ws = (char*)d_ws;
    f16*   HINIT = (f16*)(ws);
    float* CINIT = (float*)(ws + OFF_CINIT);
    f16*   WSTR  = (f16*)(ws + OFF_WSTR);
    f16*   PWPJ  = (f16*)(ws + OFF_PWPJ);

    hipLaunchKernelGGL(k_init,  dim3(10240), dim3(256), 0, stream,
                       noise, targ, msk, Wit, bit, Wtk, btk, HINIT, CINIT);
    hipLaunchKernelGGL(k_pack,  dim3(3220), dim3(256), 0, stream,
                       Wih0, Whh0, bl0, Wih1, Whh1, bl1, Wp, bpj, WSTR, PWPJ);
    hipLaunchKernelGGL(lstm_main, dim3(128), dim3(1024), 0, stream,
                       HINIT, CINIT, WSTR, PWPJ, lens, (float*)d_out);
}